// Round 14
// baseline (329.810 us; speedup 1.0000x reference)
//
#include <hip/hip_runtime.h>
#include <hip/hip_fp16.h>

#define NN 100000
#define NE 1600000
#define BK 256           // nodes per bucket (391 bfill blocks)
#define BKSH 8           // log2(BK)
#define NBKT 391         // ceil(NN/BK)
#define SLOT 4608        // per-bucket edge capacity (mean 4096, +8 sigma)
#define SRCMASK 0x1FFFF  // 17 bits (NN < 131072)

typedef _Float16 half2v __attribute__((ext_vector_type(2)));

__device__ inline float dot2acc(unsigned int a, unsigned int b, float c) {
#if __has_builtin(__builtin_amdgcn_fdot2)
    union { unsigned int u; half2v h; } ua, ub;
    ua.u = a; ub.u = b;
    return __builtin_amdgcn_fdot2(ua.h, ub.h, c, false);
#else
    float2 fa = __half22float2(*(const __half2*)&a);
    float2 fb = __half22float2(*(const __half2*)&b);
    return c + fa.x * fb.x + fa.y * fb.y;
#endif
}

__device__ inline int wave_incl_scan(int v, int lane) {
#pragma unroll
    for (int off = 1; off < 64; off <<= 1) {
        int t = __shfl_up(v, off, 64);
        if (lane >= off) v += t;
    }
    return v;
}

// ---------------- CSR build (R20-exact: 4096-tile windowed bscatter) ----------------
// Plateau config after 8 variants: tiles {2048,4096,8192}, BK {256,512},
// LDS-reorder vs windowed, global hist/scatter all tied or lost vs this.

__global__ __launch_bounds__(512) void bscatter_kernel(const int* __restrict__ src,
                                                       const int* __restrict__ dst,
                                                       int* __restrict__ bcur,
                                                       unsigned int* __restrict__ bedges,
                                                       int e) {
    __shared__ int h[512];    // per-tile bucket counts (391 used)
    __shared__ int gb[512];   // global window base per bucket
    int tid = threadIdx.x;
    int tile = blockIdx.x * 4096;
    int cnt_tile = min(4096, e - tile);
    h[tid] = 0;
    __syncthreads();
    unsigned int pk[8]; int rk[8], bk[8];
#pragma unroll
    for (int j = 0; j < 8; j++) {
        int li = tid + j * 512;
        if (li < cnt_tile) {
            int s = src[tile + li];
            int d = dst[tile + li];
            bk[j] = d >> BKSH;
            pk[j] = ((unsigned)(d & (BK - 1)) << 17) | (unsigned)s;
            rk[j] = atomicAdd(&h[bk[j]], 1);
        } else bk[j] = -1;
    }
    __syncthreads();
    {   // one global atomic per nonempty bucket; no scan needed
        int c = h[tid];
        if (c > 0) gb[tid] = atomicAdd(&bcur[tid], c);
    }
    __syncthreads();
#pragma unroll
    for (int j = 0; j < 8; j++)
        if (bk[j] >= 0)
            bedges[(size_t)bk[j] * SLOT + gb[bk[j]] + rk[j]] = pk[j];
}

__global__ __launch_bounds__(512) void bfill_kernel(const unsigned int* __restrict__ bedges,
                                                    const int* __restrict__ bcur,
                                                    const float* __restrict__ x,
                                                    int* __restrict__ start,
                                                    int* __restrict__ cnt,
                                                    float* __restrict__ dinv,
                                                    int* __restrict__ csr,
                                                    __half* __restrict__ g) {
    __shared__ int lcnt[BK];
    __shared__ int lstart[BK];
    __shared__ int lcur[BK];
    int q = blockIdx.x, tid = threadIdx.x;
    size_t ebase = (size_t)q * SLOT;
    int ec = bcur[q];
    int nbase = q * BK;
    if (tid < BK) lcnt[tid] = 0;
    __syncthreads();
    // SLOT/512 == 9: static unroll so pk[] stays in registers (no scratch)
    unsigned int pk[9];
#pragma unroll
    for (int k = 0; k < 9; k++) {
        int i = tid + k * 512;
        pk[k] = (i < ec) ? __builtin_nontemporal_load(&bedges[ebase + i]) : 0xFFFFFFFFu;
    }
#pragma unroll
    for (int k = 0; k < 9; k++)
        if (pk[k] != 0xFFFFFFFFu) atomicAdd(&lcnt[pk[k] >> 17], 1);
    __syncthreads();
    if (tid < 64) {   // single-wave scan: 4 buckets/lane over 256 nodes
        int b0 = tid * 4;
        int c0 = lcnt[b0], c1 = lcnt[b0 + 1], c2 = lcnt[b0 + 2], c3 = lcnt[b0 + 3];
        int s4 = c0 + c1 + c2 + c3;
        int incl = wave_incl_scan(s4, tid);
        int base = incl - s4;
        lstart[b0] = base;               lcur[b0] = base;
        lstart[b0 + 1] = base + c0;      lcur[b0 + 1] = base + c0;
        lstart[b0 + 2] = base + c0 + c1; lcur[b0 + 2] = base + c0 + c1;
        lstart[b0 + 3] = base + c0 + c1 + c2; lcur[b0 + 3] = base + c0 + c1 + c2;
    }
    __syncthreads();
    if (tid < BK) {
        int nd = nbase + tid;
        if (nd < NN) {
            start[nd] = (int)ebase + lstart[tid];
            cnt[nd]   = lcnt[tid];
            dinv[nd]  = rsqrtf((float)lcnt[tid] + 1.0f);
        }
    }
#pragma unroll
    for (int k = 0; k < 9; k++) {
        if (pk[k] != 0xFFFFFFFFu) {
            int r = atomicAdd(&lcur[pk[k] >> 17], 1);
            csr[ebase + r] = (int)(pk[k] & SRCMASK);   // ~17-entry window, L2-assembled
        }
    }
    // ---- fused prep epilogue: g0 rows for this bucket (lcnt stable since hist) ----
    int nh = NN - nbase; if (nh > BK) nh = BK;
    for (int i = tid; i < nh * 16; i += 512) {   // float4 chunks, 16 per row
        int r = i >> 4, c4 = (i & 15) << 2;
        float dvv = rsqrtf((float)lcnt[r] + 1.0f);
        size_t off = (size_t)(nbase + r) * 64 + c4;
        float4 v = *(const float4*)&x[off];
        union { __half2 h[2]; uint2 u; } pq;
        pq.h[0] = __floats2half2_rn(v.x * dvv, v.y * dvv);
        pq.h[1] = __floats2half2_rn(v.z * dvv, v.w * dvv);
        *(uint2*)&g[off] = pq.u;
    }
}

// ---------------- Fused layer 1-2: PAIRWISE gather + 64x64 transform (R20) ----------------
// 32 lanes x 4B per row -> 2 edges per vmem instr; col-pair accum as float2;
// one shfl_xor(32) per node. Self-loop counted by half 0 only.
__global__ __launch_bounds__(512) void fused_layer_kernel(const __half* __restrict__ g,
                                                          const int* __restrict__ csr,
                                                          const int* __restrict__ start,
                                                          const int* __restrict__ cnt,
                                                          const float* __restrict__ dinv,
                                                          const float* __restrict__ Wg,
                                                          const float* __restrict__ bias,
                                                          __half* __restrict__ gout, int n) {
    __shared__ uint4 wpk[8][64];   // 8KB: wpk[p][c] = half W[8p..8p+7][c]
    __shared__ __half zh[8][64];   // 1KB, one row per wave
    __shared__ float bs[64];
    int tid = threadIdx.x;
    {
        int p = tid >> 6, c = tid & 63;
        float w[8];
#pragma unroll
        for (int i = 0; i < 8; i++) w[i] = Wg[(8 * p + i) * 64 + c];
        union { __half2 h; unsigned int u; } u0, u1, u2, u3;
        u0.h = __floats2half2_rn(w[0], w[1]);
        u1.h = __floats2half2_rn(w[2], w[3]);
        u2.h = __floats2half2_rn(w[4], w[5]);
        u3.h = __floats2half2_rn(w[6], w[7]);
        wpk[p][c] = make_uint4(u0.u, u1.u, u2.u, u3.u);
    }
    if (tid < 64) bs[tid] = bias[tid];
    __syncthreads();   // only barrier: W/bias staging

    int wv = tid >> 6, lane = tid & 63;
    int hv = lane >> 5;          // half-wave index
    int c2 = lane & 31;          // col-pair index (cols 2c2, 2c2+1)
    int node = blockIdx.x * 8 + wv;
    float ax = 0.f, ay = 0.f, dv = 0.f;
    if (node < n) {
        int st = __builtin_amdgcn_readfirstlane(start[node]);
        int cn = __builtin_amdgcn_readfirstlane(cnt[node]);
        dv = dinv[node];
        {   // self loop, counted once (half 0 only)
            unsigned int sv = *(const unsigned int*)(g + (size_t)node * 64 + 2 * c2);
            float2 sf = __half22float2(*(const __half2*)&sv);
            if (hv == 0) { ax = sf.x; ay = sf.y; }
        }
        int e = 0;
        for (; e + 15 < cn; e += 16) {   // 8 dual-row loads = 16 edges in flight
            int u[16];
#pragma unroll
            for (int j = 0; j < 16; j++) u[j] = __builtin_nontemporal_load(&csr[st + e + j]);
            float2 f[8];
#pragma unroll
            for (int j = 0; j < 8; j++) {
                int us = hv ? u[2 * j + 1] : u[2 * j];
                unsigned int v = *(const unsigned int*)(g + (size_t)us * 64 + 2 * c2);
                f[j] = __half22float2(*(const __half2*)&v);
            }
            ax += ((f[0].x + f[1].x) + (f[2].x + f[3].x)) + ((f[4].x + f[5].x) + (f[6].x + f[7].x));
            ay += ((f[0].y + f[1].y) + (f[2].y + f[3].y)) + ((f[4].y + f[5].y) + (f[6].y + f[7].y));
        }
        for (; e + 7 < cn; e += 8) {     // 4 dual-row loads = 8 edges
            int u[8];
#pragma unroll
            for (int j = 0; j < 8; j++) u[j] = __builtin_nontemporal_load(&csr[st + e + j]);
            float2 f[4];
#pragma unroll
            for (int j = 0; j < 4; j++) {
                int us = hv ? u[2 * j + 1] : u[2 * j];
                unsigned int v = *(const unsigned int*)(g + (size_t)us * 64 + 2 * c2);
                f[j] = __half22float2(*(const __half2*)&v);
            }
            ax += (f[0].x + f[1].x) + (f[2].x + f[3].x);
            ay += (f[0].y + f[1].y) + (f[2].y + f[3].y);
        }
        for (; e + 1 < cn; e += 2) {
            int u0 = __builtin_nontemporal_load(&csr[st + e]);
            int u1 = __builtin_nontemporal_load(&csr[st + e + 1]);
            int us = hv ? u1 : u0;
            unsigned int v = *(const unsigned int*)(g + (size_t)us * 64 + 2 * c2);
            float2 f = __half22float2(*(const __half2*)&v);
            ax += f.x; ay += f.y;
        }
        if (e < cn) {   // odd tail: half 0 only
            int u0 = __builtin_nontemporal_load(&csr[st + e]);
            unsigned int v = *(const unsigned int*)(g + (size_t)u0 * 64 + 2 * c2);
            float2 f = __half22float2(*(const __half2*)&v);
            if (hv == 0) { ax += f.x; ay += f.y; }
        }
        ax += __shfl_xor(ax, 32, 64);   // combine halves (one op per node)
        ay += __shfl_xor(ay, 32, 64);
    }
    *(__half2*)&zh[wv][2 * c2] = __floats2half2_rn(ax, ay);   // wave-private; dup write benign
    if (node < n) {
        float t = 0.f;
#pragma unroll
        for (int p = 0; p < 8; p++) {
            uint4 wq = wpk[p][lane];                        // per-lane b128
            uint4 zq = *(const uint4*)&zh[wv][p * 8];       // uniform b128
            t = dot2acc(zq.x, wq.x, t);
            t = dot2acc(zq.y, wq.y, t);
            t = dot2acc(zq.z, wq.z, t);
            t = dot2acc(zq.w, wq.w, t);
        }
        float o = dv * t + bs[lane];
        o = fmaxf(o, 0.f);
        gout[(size_t)node * 64 + lane] = __float2half_rn(dv * o);
    }
}

// ---------------- Fused layer 3 + W4 transform (pairwise gather + mini-GEMM) ----------------
__global__ __launch_bounds__(512) void fused_last_kernel(const __half* __restrict__ g,
                                                         const int* __restrict__ csr,
                                                         const int* __restrict__ start,
                                                         const int* __restrict__ cnt,
                                                         const float* __restrict__ dinv,
                                                         const float* __restrict__ Wg,
                                                         const float* __restrict__ bias,
                                                         const float* __restrict__ W4,
                                                         __half* __restrict__ s4out, int n) {
    __shared__ uint4 wpk[8][64];   // 8KB
    __shared__ __half zh[8][64];   // 1KB (aggregated h)
    __shared__ __half z2[8][64];   // 1KB (g3 row for W4 mini-GEMM)
    __shared__ uint4 w4pk[8][16];  // 2KB
    __shared__ float bs[64];
    int tid = threadIdx.x;
    {
        int p = tid >> 6, c = tid & 63;
        float w[8];
#pragma unroll
        for (int i = 0; i < 8; i++) w[i] = Wg[(8 * p + i) * 64 + c];
        union { __half2 h; unsigned int u; } u0, u1, u2, u3;
        u0.h = __floats2half2_rn(w[0], w[1]);
        u1.h = __floats2half2_rn(w[2], w[3]);
        u2.h = __floats2half2_rn(w[4], w[5]);
        u3.h = __floats2half2_rn(w[6], w[7]);
        wpk[p][c] = make_uint4(u0.u, u1.u, u2.u, u3.u);
    }
    if (tid < 128) {   // W4 is [64][16] row-major
        int p = tid >> 4, j = tid & 15;
        float w[8];
#pragma unroll
        for (int i = 0; i < 8; i++) w[i] = W4[(8 * p + i) * 16 + j];
        union { __half2 h; unsigned int u; } u0, u1, u2, u3;
        u0.h = __floats2half2_rn(w[0], w[1]);
        u1.h = __floats2half2_rn(w[2], w[3]);
        u2.h = __floats2half2_rn(w[4], w[5]);
        u3.h = __floats2half2_rn(w[6], w[7]);
        w4pk[p][j] = make_uint4(u0.u, u1.u, u2.u, u3.u);
    }
    if (tid < 64) bs[tid] = bias[tid];
    __syncthreads();

    int wv = tid >> 6, lane = tid & 63;
    int hv = lane >> 5;
    int c2 = lane & 31;
    int node = blockIdx.x * 8 + wv;
    float ax = 0.f, ay = 0.f, dv = 0.f;
    if (node < n) {
        int st = __builtin_amdgcn_readfirstlane(start[node]);
        int cn = __builtin_amdgcn_readfirstlane(cnt[node]);
        dv = dinv[node];
        {
            unsigned int sv = *(const unsigned int*)(g + (size_t)node * 64 + 2 * c2);
            float2 sf = __half22float2(*(const __half2*)&sv);
            if (hv == 0) { ax = sf.x; ay = sf.y; }
        }
        int e = 0;
        for (; e + 15 < cn; e += 16) {
            int u[16];
#pragma unroll
            for (int j = 0; j < 16; j++) u[j] = __builtin_nontemporal_load(&csr[st + e + j]);
            float2 f[8];
#pragma unroll
            for (int j = 0; j < 8; j++) {
                int us = hv ? u[2 * j + 1] : u[2 * j];
                unsigned int v = *(const unsigned int*)(g + (size_t)us * 64 + 2 * c2);
                f[j] = __half22float2(*(const __half2*)&v);
            }
            ax += ((f[0].x + f[1].x) + (f[2].x + f[3].x)) + ((f[4].x + f[5].x) + (f[6].x + f[7].x));
            ay += ((f[0].y + f[1].y) + (f[2].y + f[3].y)) + ((f[4].y + f[5].y) + (f[6].y + f[7].y));
        }
        for (; e + 7 < cn; e += 8) {
            int u[8];
#pragma unroll
            for (int j = 0; j < 8; j++) u[j] = __builtin_nontemporal_load(&csr[st + e + j]);
            float2 f[4];
#pragma unroll
            for (int j = 0; j < 4; j++) {
                int us = hv ? u[2 * j + 1] : u[2 * j];
                unsigned int v = *(const unsigned int*)(g + (size_t)us * 64 + 2 * c2);
                f[j] = __half22float2(*(const __half2*)&v);
            }
            ax += (f[0].x + f[1].x) + (f[2].x + f[3].x);
            ay += (f[0].y + f[1].y) + (f[2].y + f[3].y);
        }
        for (; e + 1 < cn; e += 2) {
            int u0 = __builtin_nontemporal_load(&csr[st + e]);
            int u1 = __builtin_nontemporal_load(&csr[st + e + 1]);
            int us = hv ? u1 : u0;
            unsigned int v = *(const unsigned int*)(g + (size_t)us * 64 + 2 * c2);
            float2 f = __half22float2(*(const __half2*)&v);
            ax += f.x; ay += f.y;
        }
        if (e < cn) {
            int u0 = __builtin_nontemporal_load(&csr[st + e]);
            unsigned int v = *(const unsigned int*)(g + (size_t)u0 * 64 + 2 * c2);
            float2 f = __half22float2(*(const __half2*)&v);
            if (hv == 0) { ax += f.x; ay += f.y; }
        }
        ax += __shfl_xor(ax, 32, 64);
        ay += __shfl_xor(ay, 32, 64);
    }
    *(__half2*)&zh[wv][2 * c2] = __floats2half2_rn(ax, ay);   // wave-private
    if (node < n) {
        float t = 0.f;
#pragma unroll
        for (int p = 0; p < 8; p++) {
            uint4 wq = wpk[p][lane];
            uint4 zq = *(const uint4*)&zh[wv][p * 8];
            t = dot2acc(zq.x, wq.x, t);
            t = dot2acc(zq.y, wq.y, t);
            t = dot2acc(zq.z, wq.z, t);
            t = dot2acc(zq.w, wq.w, t);
        }
        float o = dv * t + bs[lane];
        o = fmaxf(o, 0.f);
        z2[wv][lane] = __float2half_rn(dv * o);   // g3, wave-private
        int col = lane & 15, seg = lane >> 4;
        float t4 = 0.f;
#pragma unroll
        for (int pp = 0; pp < 2; pp++) {
            int p = seg * 2 + pp;
            uint4 wq = w4pk[p][col];
            uint4 zq = *(const uint4*)&z2[wv][p * 8];
            t4 = dot2acc(zq.x, wq.x, t4);
            t4 = dot2acc(zq.y, wq.y, t4);
            t4 = dot2acc(zq.z, wq.z, t4);
            t4 = dot2acc(zq.w, wq.w, t4);
        }
        t4 += __shfl_xor(t4, 16, 64);
        t4 += __shfl_xor(t4, 32, 64);
        if (lane < 16)
            s4out[(size_t)node * 16 + col] = __float2half_rn(t4);
    }
}

// ---------------- Layer-4 aggregate (R23: pairwise) ----------------
// s4 rows are 32B. Old: 16 lanes x 2B = 1 edge/instr. New: within each
// 16-lane node-group, sub-half 0/1 take even/odd edges, each lane reads 4B
// (2 cols) -> 2 edges per vmem instr; one shfl_xor(8) per node combines;
// fp32 output written as float2 by sub-half 0.
__global__ __launch_bounds__(256) void agg16_kernel(const __half* __restrict__ s,
                                                    const int* __restrict__ csr,
                                                    const int* __restrict__ start,
                                                    const int* __restrict__ cnt,
                                                    const float* __restrict__ dinv,
                                                    const float* __restrict__ bias,
                                                    float* __restrict__ out, int n) {
    constexpr int D = 16;
    int tid = threadIdx.x;
    int lane = tid & 63;
    int wave = tid >> 6;
    int grp = lane >> 4;         // 4 nodes per wave
    int sub = (lane >> 3) & 1;   // edge-parity half within the group
    int c2 = lane & 7;           // col pair: cols 2c2, 2c2+1
    int node = (blockIdx.x * 4 + wave) * 4 + grp;
    if (node >= n) return;
    int st = start[node];
    int cn = cnt[node];
    float ax = 0.f, ay = 0.f;
    {   // self loop, counted once (sub 0 only)
        unsigned int sv = *(const unsigned int*)(s + (size_t)node * D + 2 * c2);
        float2 sf = __half22float2(*(const __half2*)&sv);
        if (sub == 0) { ax = sf.x; ay = sf.y; }
    }
    int e = 0;
    for (; e + 7 < cn; e += 8) {
        int u[8];
#pragma unroll
        for (int j = 0; j < 8; j++) u[j] = __builtin_nontemporal_load(&csr[st + e + j]);
        float2 f[4];
#pragma unroll
        for (int j = 0; j < 4; j++) {
            int us = sub ? u[2 * j + 1] : u[2 * j];
            unsigned int v = *(const unsigned int*)(s + (size_t)us * D + 2 * c2);
            f[j] = __half22float2(*(const __half2*)&v);
        }
        ax += (f[0].x + f[1].x) + (f[2].x + f[3].x);
        ay += (f[0].y + f[1].y) + (f[2].y + f[3].y);
    }
    for (; e + 1 < cn; e += 2) {
        int u0 = __builtin_nontemporal_load(&csr[st + e]);
        int u1 = __builtin_nontemporal_load(&csr[st + e + 1]);
        int us = sub ? u1 : u0;
        unsigned int v = *(const unsigned int*)(s + (size_t)us * D + 2 * c2);
        float2 f = __half22float2(*(const __half2*)&v);
        ax += f.x; ay += f.y;
    }
    if (e < cn) {   // odd tail: sub 0 only
        int u0 = __builtin_nontemporal_load(&csr[st + e]);
        unsigned int v = *(const unsigned int*)(s + (size_t)u0 * D + 2 * c2);
        float2 f = __half22float2(*(const __half2*)&v);
        if (sub == 0) { ax += f.x; ay += f.y; }
    }
    ax += __shfl_xor(ax, 8, 64);   // combine edge-parity halves (stays in group)
    ay += __shfl_xor(ay, 8, 64);
    if (sub == 0) {
        float dvv = dinv[node];
        float2 b2 = *(const float2*)&bias[2 * c2];
        float2 o2 = make_float2(dvv * ax + b2.x, dvv * ay + b2.y);
        __builtin_nontemporal_store(o2.x, out + (size_t)node * D + 2 * c2);
        __builtin_nontemporal_store(o2.y, out + (size_t)node * D + 2 * c2 + 1);
    }
}

// ---------------- launch ----------------

extern "C" void kernel_launch(void* const* d_in, const int* in_sizes, int n_in,
                              void* d_out, int out_size, void* d_ws, size_t ws_size,
                              hipStream_t stream) {
    const float* x  = (const float*)d_in[0];
    const int* ei   = (const int*)d_in[1];
    const float* W1 = (const float*)d_in[2];
    const float* b1 = (const float*)d_in[3];
    const float* W2 = (const float*)d_in[4];
    const float* b2 = (const float*)d_in[5];
    const float* W3 = (const float*)d_in[6];
    const float* b3 = (const float*)d_in[7];
    const float* W4 = (const float*)d_in[8];
    const float* b4 = (const float*)d_in[9];
    const int* src = ei;
    const int* dst = ei + NE;

    char* w = (char*)d_ws;
    float* dinv  = (float*)w;          w += (size_t)NN * 4;
    int* cnt     = (int*)w;            w += (size_t)NN * 4;
    int* start   = (int*)w;            w += (size_t)NN * 4;
    int* bcur    = (int*)w;            w += (size_t)512 * 4;
    int* csr     = (int*)w;            w += (size_t)NBKT * SLOT * 4;   // slotted, gaps ok
    __half* gA   = (__half*)w;         w += (size_t)NN * 64 * 2;
    __half* gB   = (__half*)w;         w += (size_t)NN * 64 * 2;
    __half* s4   = (__half*)w;         w += (size_t)NN * 16 * 2;
    unsigned int* bedges = (unsigned int*)w;  w += (size_t)NBKT * SLOT * 4;

    hipMemsetAsync(bcur, 0, 512 * sizeof(int), stream);
    bscatter_kernel<<<(NE + 4095) / 4096, 512, 0, stream>>>(src, dst, bcur, bedges, NE);
    bfill_kernel<<<NBKT, 512, 0, stream>>>(bedges, bcur, x, start, cnt, dinv, csr, gA);

    const int FB = (NN + 7) / 8;      // 12500 blocks, 1 node/wave
    fused_layer_kernel<<<FB, 512, 0, stream>>>(gA, csr, start, cnt, dinv, W1, b1, gB, NN);
    fused_layer_kernel<<<FB, 512, 0, stream>>>(gB, csr, start, cnt, dinv, W2, b2, gA, NN);
    fused_last_kernel<<<FB, 512, 0, stream>>>(gA, csr, start, cnt, dinv, W3, b3, W4, s4, NN);

    const int AB16 = (NN + 15) / 16;
    agg16_kernel<<<AB16, 256, 0, stream>>>(s4, csr, start, cnt, dinv, b4, (float*)d_out, NN);
}

// Round 15
// 304.565 us; speedup vs baseline: 1.0829x; 1.0829x over previous
//
#include <hip/hip_runtime.h>
#include <hip/hip_fp16.h>

#define NN 100000
#define NE 1600000
#define BK 256           // nodes per bucket (391 bfill blocks)
#define BKSH 8           // log2(BK)
#define NBKT 391         // ceil(NN/BK)
#define SLOT 4608        // per-bucket edge capacity (mean 4096, +8 sigma)
#define SRCMASK 0x1FFFF  // 17 bits (NN < 131072)

typedef _Float16 half2v __attribute__((ext_vector_type(2)));

__device__ inline float dot2acc(unsigned int a, unsigned int b, float c) {
#if __has_builtin(__builtin_amdgcn_fdot2)
    union { unsigned int u; half2v h; } ua, ub;
    ua.u = a; ub.u = b;
    return __builtin_amdgcn_fdot2(ua.h, ub.h, c, false);
#else
    float2 fa = __half22float2(*(const __half2*)&a);
    float2 fb = __half22float2(*(const __half2*)&b);
    return c + fa.x * fb.x + fa.y * fb.y;
#endif
}

__device__ inline int wave_incl_scan(int v, int lane) {
#pragma unroll
    for (int off = 1; off < 64; off <<= 1) {
        int t = __shfl_up(v, off, 64);
        if (lane >= off) v += t;
    }
    return v;
}

// ---------------- CSR build (R18-exact: windowed writes, LDS hist, no global atomics) ----------------
// Plateau config after 8 variants: tiles {2048,4096,8192}, BK {256,512},
// LDS-reorder vs windowed, global hist/scatter all tied or lost vs this.
// Key HW lessons encoded here: (1) fully-random 4B scatters amplify to
// 64B/store (R17: 118MB written); (2) random-address global atomics cost a
// full line each (R19: +26us); (3) nontemporal stores defeat L2
// write-assembly of windowed scatters (R21: +30us). Windowed bucket writes
// with plain stores are the only pattern that avoids all three.

__global__ __launch_bounds__(512) void bscatter_kernel(const int* __restrict__ src,
                                                       const int* __restrict__ dst,
                                                       int* __restrict__ bcur,
                                                       unsigned int* __restrict__ bedges,
                                                       int e) {
    __shared__ int h[512];    // per-tile bucket counts (391 used)
    __shared__ int gb[512];   // global window base per bucket
    int tid = threadIdx.x;
    int tile = blockIdx.x * 4096;
    int cnt_tile = min(4096, e - tile);
    h[tid] = 0;
    __syncthreads();
    unsigned int pk[8]; int rk[8], bk[8];
#pragma unroll
    for (int j = 0; j < 8; j++) {
        int li = tid + j * 512;
        if (li < cnt_tile) {
            int s = src[tile + li];
            int d = dst[tile + li];
            bk[j] = d >> BKSH;
            pk[j] = ((unsigned)(d & (BK - 1)) << 17) | (unsigned)s;
            rk[j] = atomicAdd(&h[bk[j]], 1);
        } else bk[j] = -1;
    }
    __syncthreads();
    {   // one global atomic per nonempty bucket; no scan needed
        int c = h[tid];
        if (c > 0) gb[tid] = atomicAdd(&bcur[tid], c);
    }
    __syncthreads();
#pragma unroll
    for (int j = 0; j < 8; j++)
        if (bk[j] >= 0)
            bedges[(size_t)bk[j] * SLOT + gb[bk[j]] + rk[j]] = pk[j];
}

__global__ __launch_bounds__(512) void bfill_kernel(const unsigned int* __restrict__ bedges,
                                                    const int* __restrict__ bcur,
                                                    const float* __restrict__ x,
                                                    int* __restrict__ start,
                                                    int* __restrict__ cnt,
                                                    float* __restrict__ dinv,
                                                    int* __restrict__ csr,
                                                    __half* __restrict__ g) {
    __shared__ int lcnt[BK];
    __shared__ int lstart[BK];
    __shared__ int lcur[BK];
    int q = blockIdx.x, tid = threadIdx.x;
    size_t ebase = (size_t)q * SLOT;
    int ec = bcur[q];
    int nbase = q * BK;
    if (tid < BK) lcnt[tid] = 0;
    __syncthreads();
    // SLOT/512 == 9: static unroll so pk[] stays in registers (no scratch)
    unsigned int pk[9];
#pragma unroll
    for (int k = 0; k < 9; k++) {
        int i = tid + k * 512;
        pk[k] = (i < ec) ? __builtin_nontemporal_load(&bedges[ebase + i]) : 0xFFFFFFFFu;
    }
#pragma unroll
    for (int k = 0; k < 9; k++)
        if (pk[k] != 0xFFFFFFFFu) atomicAdd(&lcnt[pk[k] >> 17], 1);
    __syncthreads();
    if (tid < 64) {   // single-wave scan: 4 buckets/lane over 256 nodes
        int b0 = tid * 4;
        int c0 = lcnt[b0], c1 = lcnt[b0 + 1], c2 = lcnt[b0 + 2], c3 = lcnt[b0 + 3];
        int s4 = c0 + c1 + c2 + c3;
        int incl = wave_incl_scan(s4, tid);
        int base = incl - s4;
        lstart[b0] = base;               lcur[b0] = base;
        lstart[b0 + 1] = base + c0;      lcur[b0 + 1] = base + c0;
        lstart[b0 + 2] = base + c0 + c1; lcur[b0 + 2] = base + c0 + c1;
        lstart[b0 + 3] = base + c0 + c1 + c2; lcur[b0 + 3] = base + c0 + c1 + c2;
    }
    __syncthreads();
    if (tid < BK) {
        int nd = nbase + tid;
        if (nd < NN) {
            start[nd] = (int)ebase + lstart[tid];
            cnt[nd]   = lcnt[tid];
            dinv[nd]  = rsqrtf((float)lcnt[tid] + 1.0f);
        }
    }
#pragma unroll
    for (int k = 0; k < 9; k++) {
        if (pk[k] != 0xFFFFFFFFu) {
            int r = atomicAdd(&lcur[pk[k] >> 17], 1);
            csr[ebase + r] = (int)(pk[k] & SRCMASK);   // ~17-entry window, L2-assembled
        }
    }
    // ---- fused prep epilogue: g0 rows for this bucket (lcnt stable since hist) ----
    int nh = NN - nbase; if (nh > BK) nh = BK;
    for (int i = tid; i < nh * 16; i += 512) {   // float4 chunks, 16 per row
        int r = i >> 4, c4 = (i & 15) << 2;
        float dvv = rsqrtf((float)lcnt[r] + 1.0f);
        size_t off = (size_t)(nbase + r) * 64 + c4;
        float4 v = *(const float4*)&x[off];
        union { __half2 h[2]; uint2 u; } pq;
        pq.h[0] = __floats2half2_rn(v.x * dvv, v.y * dvv);
        pq.h[1] = __floats2half2_rn(v.z * dvv, v.w * dvv);
        *(uint2*)&g[off] = pq.u;
    }
}

// ---------------- Fused layer 1-2: PAIRWISE gather + 64x64 transform (R20) ----------------
// 32 lanes x 4B per row -> 2 edges per vmem instr (row = 128B = 2 segments
// either way, so instruction count halves at constant segment count);
// col-pair accum as float2; one shfl_xor(32) per node. Self-loop: half 0 only.
__global__ __launch_bounds__(512) void fused_layer_kernel(const __half* __restrict__ g,
                                                          const int* __restrict__ csr,
                                                          const int* __restrict__ start,
                                                          const int* __restrict__ cnt,
                                                          const float* __restrict__ dinv,
                                                          const float* __restrict__ Wg,
                                                          const float* __restrict__ bias,
                                                          __half* __restrict__ gout, int n) {
    __shared__ uint4 wpk[8][64];   // 8KB: wpk[p][c] = half W[8p..8p+7][c]
    __shared__ __half zh[8][64];   // 1KB, one row per wave
    __shared__ float bs[64];
    int tid = threadIdx.x;
    {
        int p = tid >> 6, c = tid & 63;
        float w[8];
#pragma unroll
        for (int i = 0; i < 8; i++) w[i] = Wg[(8 * p + i) * 64 + c];
        union { __half2 h; unsigned int u; } u0, u1, u2, u3;
        u0.h = __floats2half2_rn(w[0], w[1]);
        u1.h = __floats2half2_rn(w[2], w[3]);
        u2.h = __floats2half2_rn(w[4], w[5]);
        u3.h = __floats2half2_rn(w[6], w[7]);
        wpk[p][c] = make_uint4(u0.u, u1.u, u2.u, u3.u);
    }
    if (tid < 64) bs[tid] = bias[tid];
    __syncthreads();   // only barrier: W/bias staging

    int wv = tid >> 6, lane = tid & 63;
    int hv = lane >> 5;          // half-wave index
    int c2 = lane & 31;          // col-pair index (cols 2c2, 2c2+1)
    int node = blockIdx.x * 8 + wv;
    float ax = 0.f, ay = 0.f, dv = 0.f;
    if (node < n) {
        int st = __builtin_amdgcn_readfirstlane(start[node]);
        int cn = __builtin_amdgcn_readfirstlane(cnt[node]);
        dv = dinv[node];
        {   // self loop, counted once (half 0 only)
            unsigned int sv = *(const unsigned int*)(g + (size_t)node * 64 + 2 * c2);
            float2 sf = __half22float2(*(const __half2*)&sv);
            if (hv == 0) { ax = sf.x; ay = sf.y; }
        }
        int e = 0;
        for (; e + 15 < cn; e += 16) {   // 8 dual-row loads = 16 edges in flight
            int u[16];
#pragma unroll
            for (int j = 0; j < 16; j++) u[j] = __builtin_nontemporal_load(&csr[st + e + j]);
            float2 f[8];
#pragma unroll
            for (int j = 0; j < 8; j++) {
                int us = hv ? u[2 * j + 1] : u[2 * j];
                unsigned int v = *(const unsigned int*)(g + (size_t)us * 64 + 2 * c2);
                f[j] = __half22float2(*(const __half2*)&v);
            }
            ax += ((f[0].x + f[1].x) + (f[2].x + f[3].x)) + ((f[4].x + f[5].x) + (f[6].x + f[7].x));
            ay += ((f[0].y + f[1].y) + (f[2].y + f[3].y)) + ((f[4].y + f[5].y) + (f[6].y + f[7].y));
        }
        for (; e + 7 < cn; e += 8) {     // 4 dual-row loads = 8 edges
            int u[8];
#pragma unroll
            for (int j = 0; j < 8; j++) u[j] = __builtin_nontemporal_load(&csr[st + e + j]);
            float2 f[4];
#pragma unroll
            for (int j = 0; j < 4; j++) {
                int us = hv ? u[2 * j + 1] : u[2 * j];
                unsigned int v = *(const unsigned int*)(g + (size_t)us * 64 + 2 * c2);
                f[j] = __half22float2(*(const __half2*)&v);
            }
            ax += (f[0].x + f[1].x) + (f[2].x + f[3].x);
            ay += (f[0].y + f[1].y) + (f[2].y + f[3].y);
        }
        for (; e + 1 < cn; e += 2) {
            int u0 = __builtin_nontemporal_load(&csr[st + e]);
            int u1 = __builtin_nontemporal_load(&csr[st + e + 1]);
            int us = hv ? u1 : u0;
            unsigned int v = *(const unsigned int*)(g + (size_t)us * 64 + 2 * c2);
            float2 f = __half22float2(*(const __half2*)&v);
            ax += f.x; ay += f.y;
        }
        if (e < cn) {   // odd tail: half 0 only
            int u0 = __builtin_nontemporal_load(&csr[st + e]);
            unsigned int v = *(const unsigned int*)(g + (size_t)u0 * 64 + 2 * c2);
            float2 f = __half22float2(*(const __half2*)&v);
            if (hv == 0) { ax += f.x; ay += f.y; }
        }
        ax += __shfl_xor(ax, 32, 64);   // combine halves (one op per node)
        ay += __shfl_xor(ay, 32, 64);
    }
    *(__half2*)&zh[wv][2 * c2] = __floats2half2_rn(ax, ay);   // wave-private; dup write benign
    if (node < n) {
        float t = 0.f;
#pragma unroll
        for (int p = 0; p < 8; p++) {
            uint4 wq = wpk[p][lane];                        // per-lane b128
            uint4 zq = *(const uint4*)&zh[wv][p * 8];       // uniform b128
            t = dot2acc(zq.x, wq.x, t);
            t = dot2acc(zq.y, wq.y, t);
            t = dot2acc(zq.z, wq.z, t);
            t = dot2acc(zq.w, wq.w, t);
        }
        float o = dv * t + bs[lane];
        o = fmaxf(o, 0.f);
        gout[(size_t)node * 64 + lane] = __float2half_rn(dv * o);
    }
}

// ---------------- Fused layer 3 + W4 transform (pairwise gather + mini-GEMM) ----------------
__global__ __launch_bounds__(512) void fused_last_kernel(const __half* __restrict__ g,
                                                         const int* __restrict__ csr,
                                                         const int* __restrict__ start,
                                                         const int* __restrict__ cnt,
                                                         const float* __restrict__ dinv,
                                                         const float* __restrict__ Wg,
                                                         const float* __restrict__ bias,
                                                         const float* __restrict__ W4,
                                                         __half* __restrict__ s4out, int n) {
    __shared__ uint4 wpk[8][64];   // 8KB
    __shared__ __half zh[8][64];   // 1KB (aggregated h)
    __shared__ __half z2[8][64];   // 1KB (g3 row for W4 mini-GEMM)
    __shared__ uint4 w4pk[8][16];  // 2KB
    __shared__ float bs[64];
    int tid = threadIdx.x;
    {
        int p = tid >> 6, c = tid & 63;
        float w[8];
#pragma unroll
        for (int i = 0; i < 8; i++) w[i] = Wg[(8 * p + i) * 64 + c];
        union { __half2 h; unsigned int u; } u0, u1, u2, u3;
        u0.h = __floats2half2_rn(w[0], w[1]);
        u1.h = __floats2half2_rn(w[2], w[3]);
        u2.h = __floats2half2_rn(w[4], w[5]);
        u3.h = __floats2half2_rn(w[6], w[7]);
        wpk[p][c] = make_uint4(u0.u, u1.u, u2.u, u3.u);
    }
    if (tid < 128) {   // W4 is [64][16] row-major
        int p = tid >> 4, j = tid & 15;
        float w[8];
#pragma unroll
        for (int i = 0; i < 8; i++) w[i] = W4[(8 * p + i) * 16 + j];
        union { __half2 h; unsigned int u; } u0, u1, u2, u3;
        u0.h = __floats2half2_rn(w[0], w[1]);
        u1.h = __floats2half2_rn(w[2], w[3]);
        u2.h = __floats2half2_rn(w[4], w[5]);
        u3.h = __floats2half2_rn(w[6], w[7]);
        w4pk[p][j] = make_uint4(u0.u, u1.u, u2.u, u3.u);
    }
    if (tid < 64) bs[tid] = bias[tid];
    __syncthreads();

    int wv = tid >> 6, lane = tid & 63;
    int hv = lane >> 5;
    int c2 = lane & 31;
    int node = blockIdx.x * 8 + wv;
    float ax = 0.f, ay = 0.f, dv = 0.f;
    if (node < n) {
        int st = __builtin_amdgcn_readfirstlane(start[node]);
        int cn = __builtin_amdgcn_readfirstlane(cnt[node]);
        dv = dinv[node];
        {
            unsigned int sv = *(const unsigned int*)(g + (size_t)node * 64 + 2 * c2);
            float2 sf = __half22float2(*(const __half2*)&sv);
            if (hv == 0) { ax = sf.x; ay = sf.y; }
        }
        int e = 0;
        for (; e + 15 < cn; e += 16) {
            int u[16];
#pragma unroll
            for (int j = 0; j < 16; j++) u[j] = __builtin_nontemporal_load(&csr[st + e + j]);
            float2 f[8];
#pragma unroll
            for (int j = 0; j < 8; j++) {
                int us = hv ? u[2 * j + 1] : u[2 * j];
                unsigned int v = *(const unsigned int*)(g + (size_t)us * 64 + 2 * c2);
                f[j] = __half22float2(*(const __half2*)&v);
            }
            ax += ((f[0].x + f[1].x) + (f[2].x + f[3].x)) + ((f[4].x + f[5].x) + (f[6].x + f[7].x));
            ay += ((f[0].y + f[1].y) + (f[2].y + f[3].y)) + ((f[4].y + f[5].y) + (f[6].y + f[7].y));
        }
        for (; e + 7 < cn; e += 8) {
            int u[8];
#pragma unroll
            for (int j = 0; j < 8; j++) u[j] = __builtin_nontemporal_load(&csr[st + e + j]);
            float2 f[4];
#pragma unroll
            for (int j = 0; j < 4; j++) {
                int us = hv ? u[2 * j + 1] : u[2 * j];
                unsigned int v = *(const unsigned int*)(g + (size_t)us * 64 + 2 * c2);
                f[j] = __half22float2(*(const __half2*)&v);
            }
            ax += (f[0].x + f[1].x) + (f[2].x + f[3].x);
            ay += (f[0].y + f[1].y) + (f[2].y + f[3].y);
        }
        for (; e + 1 < cn; e += 2) {
            int u0 = __builtin_nontemporal_load(&csr[st + e]);
            int u1 = __builtin_nontemporal_load(&csr[st + e + 1]);
            int us = hv ? u1 : u0;
            unsigned int v = *(const unsigned int*)(g + (size_t)us * 64 + 2 * c2);
            float2 f = __half22float2(*(const __half2*)&v);
            ax += f.x; ay += f.y;
        }
        if (e < cn) {
            int u0 = __builtin_nontemporal_load(&csr[st + e]);
            unsigned int v = *(const unsigned int*)(g + (size_t)u0 * 64 + 2 * c2);
            float2 f = __half22float2(*(const __half2*)&v);
            if (hv == 0) { ax += f.x; ay += f.y; }
        }
        ax += __shfl_xor(ax, 32, 64);
        ay += __shfl_xor(ay, 32, 64);
    }
    *(__half2*)&zh[wv][2 * c2] = __floats2half2_rn(ax, ay);   // wave-private
    if (node < n) {
        float t = 0.f;
#pragma unroll
        for (int p = 0; p < 8; p++) {
            uint4 wq = wpk[p][lane];
            uint4 zq = *(const uint4*)&zh[wv][p * 8];
            t = dot2acc(zq.x, wq.x, t);
            t = dot2acc(zq.y, wq.y, t);
            t = dot2acc(zq.z, wq.z, t);
            t = dot2acc(zq.w, wq.w, t);
        }
        float o = dv * t + bs[lane];
        o = fmaxf(o, 0.f);
        z2[wv][lane] = __float2half_rn(dv * o);   // g3, wave-private
        int col = lane & 15, seg = lane >> 4;
        float t4 = 0.f;
#pragma unroll
        for (int pp = 0; pp < 2; pp++) {
            int p = seg * 2 + pp;
            uint4 wq = w4pk[p][col];
            uint4 zq = *(const uint4*)&z2[wv][p * 8];
            t4 = dot2acc(zq.x, wq.x, t4);
            t4 = dot2acc(zq.y, wq.y, t4);
            t4 = dot2acc(zq.z, wq.z, t4);
            t4 = dot2acc(zq.w, wq.w, t4);
        }
        t4 += __shfl_xor(t4, 16, 64);
        t4 += __shfl_xor(t4, 32, 64);
        if (lane < 16)
            s4out[(size_t)node * 16 + col] = __float2half_rn(t4);
    }
}

// ---------------- Layer-4 aggregate: out = dinv*(sum s4) + b4, fp32 ----------------
// Scalar 2B/lane gather is optimal here: 16 lanes x 2B = ONE 32B segment per
// edge, 4 edges/wave-instr. (R23's pairwise split doubled segments/instr at
// constant instr count -> ~2x slower; reverted.)
__global__ __launch_bounds__(256) void agg16_kernel(const __half* __restrict__ s,
                                                    const int* __restrict__ csr,
                                                    const int* __restrict__ start,
                                                    const int* __restrict__ cnt,
                                                    const float* __restrict__ dinv,
                                                    const float* __restrict__ bias,
                                                    float* __restrict__ out, int n) {
    constexpr int D = 16;
    int tid = threadIdx.x;
    int lane = tid & 63;
    int wave = tid >> 6;
    int col = lane % D;
    int grp = lane / D;
    int node = (blockIdx.x * 4 + wave) * 4 + grp;
    if (node >= n) return;
    int st = start[node];
    int cn = cnt[node];
    float acc = __half2float(s[(size_t)node * D + col]);  // self loop
    int e = 0;
    for (; e + 7 < cn; e += 8) {
        int u[8]; float a[8];
#pragma unroll
        for (int j = 0; j < 8; j++) u[j] = __builtin_nontemporal_load(&csr[st + e + j]);
#pragma unroll
        for (int j = 0; j < 8; j++) a[j] = __half2float(s[(size_t)u[j] * D + col]);
        acc += ((a[0] + a[1]) + (a[2] + a[3])) + ((a[4] + a[5]) + (a[6] + a[7]));
    }
    for (; e + 3 < cn; e += 4) {
        int u0 = __builtin_nontemporal_load(&csr[st + e + 0]);
        int u1 = __builtin_nontemporal_load(&csr[st + e + 1]);
        int u2 = __builtin_nontemporal_load(&csr[st + e + 2]);
        int u3 = __builtin_nontemporal_load(&csr[st + e + 3]);
        float a0 = __half2float(s[(size_t)u0 * D + col]);
        float a1 = __half2float(s[(size_t)u1 * D + col]);
        float a2 = __half2float(s[(size_t)u2 * D + col]);
        float a3 = __half2float(s[(size_t)u3 * D + col]);
        acc += (a0 + a1) + (a2 + a3);
    }
    for (; e < cn; e++) {
        int u = __builtin_nontemporal_load(&csr[st + e]);
        acc += __half2float(s[(size_t)u * D + col]);
    }
    float o = dinv[node] * acc + bias[col];
    __builtin_nontemporal_store(o, out + (size_t)node * D + col);
}

// ---------------- launch ----------------

extern "C" void kernel_launch(void* const* d_in, const int* in_sizes, int n_in,
                              void* d_out, int out_size, void* d_ws, size_t ws_size,
                              hipStream_t stream) {
    const float* x  = (const float*)d_in[0];
    const int* ei   = (const int*)d_in[1];
    const float* W1 = (const float*)d_in[2];
    const float* b1 = (const float*)d_in[3];
    const float* W2 = (const float*)d_in[4];
    const float* b2 = (const float*)d_in[5];
    const float* W3 = (const float*)d_in[6];
    const float* b3 = (const float*)d_in[7];
    const float* W4 = (const float*)d_in[8];
    const float* b4 = (const float*)d_in[9];
    const int* src = ei;
    const int* dst = ei + NE;

    char* w = (char*)d_ws;
    float* dinv  = (float*)w;          w += (size_t)NN * 4;
    int* cnt     = (int*)w;            w += (size_t)NN * 4;
    int* start   = (int*)w;            w += (size_t)NN * 4;
    int* bcur    = (int*)w;            w += (size_t)512 * 4;
    int* csr     = (int*)w;            w += (size_t)NBKT * SLOT * 4;   // slotted, gaps ok
    __half* gA   = (__half*)w;         w += (size_t)NN * 64 * 2;
    __half* gB   = (__half*)w;         w += (size_t)NN * 64 * 2;
    __half* s4   = (__half*)w;         w += (size_t)NN * 16 * 2;
    unsigned int* bedges = (unsigned int*)w;  w += (size_t)NBKT * SLOT * 4;

    hipMemsetAsync(bcur, 0, 512 * sizeof(int), stream);
    bscatter_kernel<<<(NE + 4095) / 4096, 512, 0, stream>>>(src, dst, bcur, bedges, NE);
    bfill_kernel<<<NBKT, 512, 0, stream>>>(bedges, bcur, x, start, cnt, dinv, csr, gA);

    const int FB = (NN + 7) / 8;      // 12500 blocks, 1 node/wave
    fused_layer_kernel<<<FB, 512, 0, stream>>>(gA, csr, start, cnt, dinv, W1, b1, gB, NN);
    fused_layer_kernel<<<FB, 512, 0, stream>>>(gB, csr, start, cnt, dinv, W2, b2, gA, NN);
    fused_last_kernel<<<FB, 512, 0, stream>>>(gA, csr, start, cnt, dinv, W3, b3, W4, s4, NN);

    const int AB16 = (NN + 15) / 16;
    agg16_kernel<<<AB16, 256, 0, stream>>>(s4, csr, start, cnt, dinv, b4, (float*)d_out, NN);
}